// Round 3
// baseline (57.729 us; speedup 1.0000x reference)
//
#include <hip/hip_runtime.h>

#define N_LAYERS 512
#define DEL_Z (0.9f / 512.0f)
#define BODY 4                    // layers per constant block
#define NBODY (N_LAYERS / BODY)   // 128 blocks
#define BSTRIDE (BODY * 5)        // 20 floats per block: [c0 x4][c1 x4][i1 x4][c3 x4][c4 x4]

typedef float f32x16 __attribute__((ext_vector_type(16)));
typedef float f32x4  __attribute__((ext_vector_type(4)));

// Stage 1: per-layer wave-uniform constants, blocked layout (4 layers / 20 floats per body)
//   c0 = 1 + g,  g = 1 - b2/b1
//   c1 = g*inv1 - DEL_Z*inv2,   inv1 = 1/(PiT*(1-z)), inv2 = inv1/(1-z)
//   i1 = inv1
//   c3 = inv1^2 - inv2/PiT + 1/b1^2
//   c4 = z^2 / b1               (MU^2 == 1; 1/omega^2 applied per-thread)
__global__ __launch_bounds__(256) void metric_setup_kernel(
    const float* __restrict__ PiT_p, const float* __restrict__ B,
    float* __restrict__ C)
{
    const int l = blockIdx.x * 256 + threadIdx.x;
    if (l >= N_LAYERS) return;
    const float PiT  = PiT_p[0];
    const float z    = DEL_Z * (float)l;      // Z_INI == 0
    const float b1   = B[l];
    const float b2   = B[l + 1];
    const float omz  = 1.0f - z;
    const float inv1 = 1.0f / (PiT * omz);
    const float inv2 = inv1 / omz;
    const float g    = 1.0f - b2 / b1;
    const int body = l >> 2, j = l & 3;
    float* p = C + body * BSTRIDE;
    p[j]      = 1.0f + g;
    p[4 + j]  = g * inv1 - DEL_Z * inv2;
    p[8 + j]  = inv1;
    p[12 + j] = inv1 * inv1 - inv2 / PiT + 1.0f / (b1 * b1);
    p[16 + j] = z * z / b1;
}

// One scan step (exact algebra of the reference):
//   Rn = c0*Re + c1 + 2*DEL_Z*om*Im*(Re + i1)
//   Im = c0*Im + DEL_Z*om*(Im^2 - (Rn+i1)^2 + c3 - c4/om^2)
#define STEP(AX, BX, J)                                           \
    {                                                             \
        const float c0 = (AX)[(J)];                               \
        const float c1 = (AX)[4 + (J)];                           \
        const float i1 = (AX)[8 + (J)];                           \
        const float c3 = (AX)[12 + (J)];                          \
        const float c4 = (BX)[(J)];                               \
        const float t  = Re + i1;                                 \
        const float a  = fmaf(c0, Re, c1);                        \
        const float Rn = fmaf(dz2om * Im, t, a);                  \
        const float u  = Rn + i1;                                 \
        float s = fmaf(Im, Im, c3);                               \
        s = fmaf(-c4, iom2, s);                                   \
        const float bb = c0 * Im;                                 \
        s = fmaf(-u, u, s);                                       \
        Im = fmaf(dzom, s, bb);                                   \
        Re = Rn;                                                  \
    }

#define LOAD_BODY(AX, BX, P)                                              \
    asm volatile("s_load_dwordx16 %0, %2, 0x0\n\t"                        \
                 "s_load_dwordx4  %1, %2, 0x40"                           \
                 : "=s"(AX), "=s"(BX) : "s"(P));

#define WAIT_BODY(AX, BX)                                                 \
    asm volatile("s_waitcnt lgkmcnt(0)" : "+s"(AX), "+s"(BX));

__global__ __launch_bounds__(256) void metric_scan_kernel(
    const float* __restrict__ Re_s, const float* __restrict__ Im_s,
    const float* __restrict__ omega, const float* __restrict__ C,
    float* __restrict__ out, int n)
{
    const int i = blockIdx.x * 256 + threadIdx.x;
    float Re = Re_s[i];
    float Im = Im_s[i];
    const float om    = omega[i];
    const float dzom  = DEL_Z * om;
    const float dz2om = 2.0f * dzom;
    const float iom   = 1.0f / om;
    const float iom2  = iom * iom;

    // Constants live in SGPRs via s_load (SMEM pipe): zero LDS-port and zero
    // vector-L1 traffic in the inner loop. Double-buffered so each load-pair
    // is issued one body (~44 VALU instrs) ahead of its lgkmcnt(0) wait.
    f32x16 Aa, Ab;
    f32x4  Ba, Bb;
    LOAD_BODY(Aa, Ba, C);

    for (int it = 0; it < NBODY / 2; ++it) {
        const int bo1 = 2 * it + 1;
        const int bo2 = (2 * it + 2 < NBODY) ? 2 * it + 2 : NBODY - 1; // clamp: no OOB
        const float* p1 = C + bo1 * BSTRIDE;
        const float* p2 = C + bo2 * BSTRIDE;

        WAIT_BODY(Aa, Ba);            // body 2it ready
        LOAD_BODY(Ab, Bb, p1);        // prefetch body 2it+1
        #pragma unroll
        for (int j = 0; j < 4; ++j) STEP(Aa, Ba, j);

        WAIT_BODY(Ab, Bb);            // body 2it+1 ready
        LOAD_BODY(Aa, Ba, p2);        // prefetch body 2it+2
        #pragma unroll
        for (int j = 0; j < 4; ++j) STEP(Ab, Bb, j);
    }

    out[i]     = Re;
    out[n + i] = Im;
}

extern "C" void kernel_launch(void* const* d_in, const int* in_sizes, int n_in,
                              void* d_out, int out_size, void* d_ws, size_t ws_size,
                              hipStream_t stream)
{
    const float* Re_s  = (const float*)d_in[0];
    const float* Im_s  = (const float*)d_in[1];
    const float* omega = (const float*)d_in[2];
    const float* PiT   = (const float*)d_in[3];
    const float* B     = (const float*)d_in[4];
    float* out = (float*)d_out;
    float* C   = (float*)d_ws;                 // 512*5*4 B = 10240 B scratch
    const int n = in_sizes[0];                 // 131072

    metric_setup_kernel<<<2, 256, 0, stream>>>(PiT, B, C);
    metric_scan_kernel<<<n / 256, 256, 0, stream>>>(Re_s, Im_s, omega, C, out, n);
}

// Round 4
// 29.292 us; speedup vs baseline: 1.9708x; 1.9708x over previous
//
#include <hip/hip_runtime.h>

#define N_LAYERS 512
#define DEL_Z (0.9f / 512.0f)
#define NGROUP (N_LAYERS / 4)     // 128 groups of 4 layers

// Per-layer constants (exact algebra of the reference; same as R1, c4 refolded):
//   c0  = 2 - b2/b1
//   c1  = g*inv1 - DEL_Z*inv2,  g = 1 - b2/b1, inv1 = 1/(PiT*(1-z)), inv2 = inv1/(1-z)
//   i1  = inv1
//   c3  = inv1^2 - inv2/PiT + 1/b1^2
//   c4p = DEL_Z * z^2 / b1          (MU^2 == 1; per-thread factor is -1/omega)
// Step:
//   Rn = c0*Re + c1 + 2*DEL_Z*om*Im*(Re + i1)
//   Im = c0*Im + DEL_Z*om*(Im^2 - (Rn+i1)^2 + c3) + c4p*(-1/om)

#define STEP1(RE, IM, DZOM, DZ2OM, NIOM, C0, C1, I1, C3, C4P)   \
    {                                                           \
        const float t  = (RE) + (I1);                           \
        const float a  = fmaf((C0), (RE), (C1));                \
        const float m  = (DZ2OM) * (IM);                        \
        const float Rn = fmaf(m, t, a);                         \
        const float u  = Rn + (I1);                             \
        float s = fmaf((IM), (IM), (C3));                       \
        s = fmaf(-u, u, s);                                     \
        const float q  = (C4P) * (NIOM);                        \
        const float b  = fmaf((C0), (IM), q);                   \
        (IM) = fmaf((DZOM), s, b);                              \
        (RE) = Rn;                                              \
    }

#define STEP2(C0, C1, I1, C3, C4P)                              \
    STEP1(Re0, Im0, dzom0, dz2om0, niom0, C0, C1, I1, C3, C4P)  \
    STEP1(Re1, Im1, dzom1, dz2om1, niom1, C0, C1, I1, C3, C4P)

#define GROUP4(A0, A1, A2, A3, A4)                              \
    STEP2((A0).x, (A1).x, (A2).x, (A3).x, (A4).x)               \
    STEP2((A0).y, (A1).y, (A2).y, (A3).y, (A4).y)               \
    STEP2((A0).z, (A1).z, (A2).z, (A3).z, (A4).z)               \
    STEP2((A0).w, (A1).w, (A2).w, (A3).w, (A4).w)

#define LOADG(A0, A1, A2, A3, A4, G)                            \
    {                                                           \
        const float4* cp = cg[(G)];                             \
        (A0) = cp[0]; (A1) = cp[1]; (A2) = cp[2];               \
        (A3) = cp[3]; (A4) = cp[4];                             \
    }

__global__ __launch_bounds__(256) void metric_scan_kernel(
    const float* __restrict__ Re_s, const float* __restrict__ Im_s,
    const float* __restrict__ omega, const float* __restrict__ PiT_p,
    const float* __restrict__ B, float* __restrict__ out, int n)
{
    // [group][0]=c0 x4, [1]=c1 x4, [2]=i1 x4, [3]=c3 x4, [4]=c4p x4
    __shared__ float4 cg[NGROUP][5];

    // In-block setup: 2 layers per thread.
    const float PiT = PiT_p[0];
    float* cbase = (float*)cg;
    for (int l = threadIdx.x; l < N_LAYERS; l += 256) {
        const float z    = DEL_Z * (float)l;   // Z_INI == 0
        const float b1   = B[l];
        const float b2   = B[l + 1];
        const float omz  = 1.0f - z;
        const float inv1 = 1.0f / (PiT * omz);
        const float inv2 = inv1 / omz;
        const float g    = 1.0f - b2 / b1;
        float* p = cbase + (l >> 2) * 20 + (l & 3);
        p[0]  = 1.0f + g;
        p[4]  = g * inv1 - DEL_Z * inv2;
        p[8]  = inv1;
        p[12] = inv1 * inv1 - inv2 / PiT + 1.0f / (b1 * b1);
        p[16] = DEL_Z * z * z / b1;
    }
    __syncthreads();

    // Two independent elements per thread: halves LDS traffic per element,
    // doubles per-wave ILP (two independent dependency chains).
    const int half = n >> 1;
    const int e0 = blockIdx.x * 256 + threadIdx.x;
    const int e1 = e0 + half;

    float Re0 = Re_s[e0], Im0 = Im_s[e0];
    float Re1 = Re_s[e1], Im1 = Im_s[e1];
    const float om0 = omega[e0], om1 = omega[e1];
    const float dzom0 = DEL_Z * om0, dz2om0 = 2.0f * dzom0, niom0 = -1.0f / om0;
    const float dzom1 = DEL_Z * om1, dz2om1 = 2.0f * dzom1, niom1 = -1.0f / om1;

    // Explicit double-buffered constant prefetch: load group g+1 while
    // computing group g (160 cy of FMA covers LDS broadcast latency).
    float4 Pa0, Pa1, Pa2, Pa3, Pa4;
    float4 Pb0, Pb1, Pb2, Pb3, Pb4;
    LOADG(Pa0, Pa1, Pa2, Pa3, Pa4, 0);

    for (int g = 0; g < NGROUP; g += 2) {
        LOADG(Pb0, Pb1, Pb2, Pb3, Pb4, g + 1);
        GROUP4(Pa0, Pa1, Pa2, Pa3, Pa4);
        const int gn = (g + 2 < NGROUP) ? g + 2 : NGROUP - 1;  // clamp, no OOB
        LOADG(Pa0, Pa1, Pa2, Pa3, Pa4, gn);
        GROUP4(Pb0, Pb1, Pb2, Pb3, Pb4);
    }

    out[e0]     = Re0;
    out[n + e0] = Im0;
    out[e1]     = Re1;
    out[n + e1] = Im1;
}

extern "C" void kernel_launch(void* const* d_in, const int* in_sizes, int n_in,
                              void* d_out, int out_size, void* d_ws, size_t ws_size,
                              hipStream_t stream)
{
    const float* Re_s  = (const float*)d_in[0];
    const float* Im_s  = (const float*)d_in[1];
    const float* omega = (const float*)d_in[2];
    const float* PiT   = (const float*)d_in[3];
    const float* B     = (const float*)d_in[4];
    float* out = (float*)d_out;
    const int n = in_sizes[0];                  // 131072
    const int nthreads = n / 2;                 // 2 elements per thread
    metric_scan_kernel<<<nthreads / 256, 256, 0, stream>>>(Re_s, Im_s, omega, PiT, B, out, n);
}

// Round 5
// 22.115 us; speedup vs baseline: 2.6103x; 1.3245x over previous
//
#include <hip/hip_runtime.h>

#define N_LAYERS 512
#define DEL_Z (0.9f / 512.0f)
#define NGROUP (N_LAYERS / 4)     // 128 groups of 4 layers

// Per-layer constants (exact algebra of the reference, same values as R1):
//   c0  = 1 + g,  g = 1 - b2/b1
//   c1  = g*inv1 - DEL_Z*inv2,  inv1 = 1/(PiT*(1-z)), inv2 = inv1/(1-z)
//   i1  = inv1
//   c3  = inv1^2 - inv2/PiT + 1/b1^2
//   c4p = DEL_Z * z^2 / b1          (MU^2 == 1; per-thread factor is -1/omega)
// Step:
//   Rn = c0*Re + c1 + 2*DEL_Z*om*Im*(Re + i1)
//   Im = c0*Im + DEL_Z*om*(Im^2 - (Rn+i1)^2 + c3) + c4p*(-1/om)
//
// LDS layout: [group][0]=c0.xyzw [1]=c1 [2]=i1 [3]=c3 [4]=c4p  (4 layers/group)
// -> 5 ds_read_b128 per 4 layers per wave = 1.25 LDS instr/layer (R1 had 2).
// All reads wave-uniform (broadcast). E=1 keeps 2048 waves = 2 waves/SIMD
// for latency hiding (R4's regression was dropping to 1 wave/SIMD).

#define STEP(C0, C1, I1, C3, C4P)                               \
    {                                                           \
        const float t  = Re + (I1);                             \
        const float a  = fmaf((C0), Re, (C1));                  \
        const float m  = dz2om * Im;                            \
        const float Rn = fmaf(m, t, a);                         \
        const float u  = Rn + (I1);                             \
        float s = fmaf(Im, Im, (C3));                           \
        const float q  = (C4P) * niom;                          \
        const float b  = fmaf((C0), Im, q);                     \
        s = fmaf(-u, u, s);                                     \
        Im = fmaf(dzom, s, b);                                  \
        Re = Rn;                                                \
    }

#define GROUP4(A0, A1, A2, A3, A4)                              \
    STEP((A0).x, (A1).x, (A2).x, (A3).x, (A4).x)                \
    STEP((A0).y, (A1).y, (A2).y, (A3).y, (A4).y)                \
    STEP((A0).z, (A1).z, (A2).z, (A3).z, (A4).z)                \
    STEP((A0).w, (A1).w, (A2).w, (A3).w, (A4).w)

#define LOADG(A0, A1, A2, A3, A4, G)                            \
    {                                                           \
        const float4* cp = cg[(G)];                             \
        (A0) = cp[0]; (A1) = cp[1]; (A2) = cp[2];               \
        (A3) = cp[3]; (A4) = cp[4];                             \
    }

__global__ __launch_bounds__(256) void metric_scan_kernel(
    const float* __restrict__ Re_s, const float* __restrict__ Im_s,
    const float* __restrict__ omega, const float* __restrict__ PiT_p,
    const float* __restrict__ B, float* __restrict__ out, int n)
{
    __shared__ float4 cg[NGROUP][5];   // 10240 B

    // In-block setup: 2 layers per thread.
    const float PiT = PiT_p[0];
    float* cbase = (float*)cg;
    for (int l = threadIdx.x; l < N_LAYERS; l += 256) {
        const float z    = DEL_Z * (float)l;   // Z_INI == 0
        const float b1   = B[l];
        const float b2   = B[l + 1];
        const float omz  = 1.0f - z;
        const float inv1 = 1.0f / (PiT * omz);
        const float inv2 = inv1 / omz;
        const float g    = 1.0f - b2 / b1;
        float* p = cbase + (l >> 2) * 20 + (l & 3);
        p[0]  = 1.0f + g;
        p[4]  = g * inv1 - DEL_Z * inv2;
        p[8]  = inv1;
        p[12] = inv1 * inv1 - inv2 / PiT + 1.0f / (b1 * b1);
        p[16] = DEL_Z * z * z / b1;
    }
    __syncthreads();

    const int i = blockIdx.x * 256 + threadIdx.x;
    float Re = Re_s[i];
    float Im = Im_s[i];
    const float om    = omega[i];
    const float dzom  = DEL_Z * om;
    const float dz2om = 2.0f * dzom;
    const float niom  = -1.0f / om;

    // Register double-buffer: load group g+1 while computing group g
    // (40 VALU instrs of cover per group).
    float4 Pa0, Pa1, Pa2, Pa3, Pa4;
    float4 Pb0, Pb1, Pb2, Pb3, Pb4;
    LOADG(Pa0, Pa1, Pa2, Pa3, Pa4, 0);

    for (int g = 0; g < NGROUP; g += 2) {
        LOADG(Pb0, Pb1, Pb2, Pb3, Pb4, g + 1);
        GROUP4(Pa0, Pa1, Pa2, Pa3, Pa4);
        const int gn = (g + 2 < NGROUP) ? g + 2 : NGROUP - 1;  // clamp, no OOB
        LOADG(Pa0, Pa1, Pa2, Pa3, Pa4, gn);
        GROUP4(Pb0, Pb1, Pb2, Pb3, Pb4);
    }

    out[i]     = Re;
    out[n + i] = Im;
}

extern "C" void kernel_launch(void* const* d_in, const int* in_sizes, int n_in,
                              void* d_out, int out_size, void* d_ws, size_t ws_size,
                              hipStream_t stream)
{
    const float* Re_s  = (const float*)d_in[0];
    const float* Im_s  = (const float*)d_in[1];
    const float* omega = (const float*)d_in[2];
    const float* PiT   = (const float*)d_in[3];
    const float* B     = (const float*)d_in[4];
    float* out = (float*)d_out;
    const int n = in_sizes[0];                  // 131072
    metric_scan_kernel<<<n / 256, 256, 0, stream>>>(Re_s, Im_s, omega, PiT, B, out, n);
}